// Round 2
// baseline (566.753 us; speedup 1.0000x reference)
//
#include <hip/hip_runtime.h>
#include <hip/hip_bf16.h>
#include <cmath>

#define HIDDEN 2048
#define NHEADS 32
#define NKVH   8
#define HD     64
#define BB     2
#define TSEQ   2048
#define MROWS  (BB*TSEQ)   // 4096

typedef __attribute__((ext_vector_type(8))) short bf16x8;
typedef __attribute__((ext_vector_type(4))) float f32x4;

__device__ __forceinline__ ushort f2bf(float f) {
  union { float f; unsigned u; } x; x.f = f;
  unsigned r = x.u + 0x7fffu + ((x.u >> 16) & 1u);
  return (ushort)(r >> 16);
}

__device__ __forceinline__ void async16(ushort* lds, const ushort* g) {
  __builtin_amdgcn_global_load_lds(
      (const __attribute__((address_space(1))) unsigned int*)g,
      (__attribute__((address_space(3))) unsigned int*)lds, 16, 0, 0);
}

// ---------------- fp32 -> bf16 elementwise ----------------
__global__ void cvt_kernel(const float* __restrict__ in, ushort* __restrict__ out, int n4) {
  int i = blockIdx.x * blockDim.x + threadIdx.x;
  if (i < n4) {
    float4 v = ((const float4*)in)[i];
    ushort4 o;
    o.x = f2bf(v.x); o.y = f2bf(v.y); o.z = f2bf(v.z); o.w = f2bf(v.w);
    ((ushort4*)out)[i] = o;
  }
}

// ---------------- fp32 [R][C] -> bf16 [C][R] transpose-convert ----------------
__global__ void tcvt_kernel(const float* __restrict__ in, ushort* __restrict__ out, int R, int C) {
  __shared__ float tile[32][33];
  int tx = threadIdx.x & 31, ty = threadIdx.x >> 5;   // ty 0..7
  int c0 = blockIdx.x * 32, r0 = blockIdx.y * 32;
#pragma unroll
  for (int i = 0; i < 4; ++i)
    tile[ty*4 + i][tx] = in[(size_t)(r0 + ty*4 + i) * C + c0 + tx];
  __syncthreads();
#pragma unroll
  for (int i = 0; i < 4; ++i)
    out[(size_t)(c0 + ty*4 + i) * R + r0 + tx] = f2bf(tile[tx][ty*4 + i]);
}

// ---------------- bf16 GEMM: C[M][N] = A[M][K] @ BT[N][K]^T ----------------
// OUT_MODE 0: C[m*N+n]   OUT_MODE 1 (V^T): C[((m>>11)*512 + n)*2048 + (m&2047)]
template<typename OutT, int OUT_MODE>
__global__ __launch_bounds__(256) void gemm_bt(const ushort* __restrict__ A,
                                               const ushort* __restrict__ BT,
                                               OutT* __restrict__ C,
                                               int M, int N, int K, float scale) {
  __shared__ ushort sA[128 * 32];
  __shared__ ushort sB[128 * 32];
  const int tid = threadIdx.x;
  const int w = tid >> 6, l = tid & 63;
  const int wr = w >> 1, wc = w & 1;
  const int g = l >> 4, c16 = l & 15;
  const int m0 = blockIdx.y * 128, n0 = blockIdx.x * 128;

  const int sr = l >> 2;          // staging row within 16-row stripe
  const int sc = (l & 3) * 8;     // staging col (elems)
  const ushort* gA[2]; const ushort* gB[2];
  ushort* lA[2]; ushort* lB[2];
#pragma unroll
  for (int ii = 0; ii < 2; ++ii) {
    int inst = w * 2 + ii;
    gA[ii] = A  + (size_t)(m0 + inst*16 + sr) * K + sc;
    gB[ii] = BT + (size_t)(n0 + inst*16 + sr) * K + sc;
    lA[ii] = sA + inst * 512 + l * 8;
    lB[ii] = sB + inst * 512 + l * 8;
  }

  f32x4 acc[4][4] = {};

  for (int k0 = 0; k0 < K; k0 += 32) {
    async16(lA[0], gA[0] + k0);
    async16(lA[1], gA[1] + k0);
    async16(lB[0], gB[0] + k0);
    async16(lB[1], gB[1] + k0);
    __syncthreads();
    bf16x8 a[4], b[4];
#pragma unroll
    for (int mi = 0; mi < 4; ++mi)
      a[mi] = *(const bf16x8*)(sA + (wr*64 + mi*16 + c16) * 32 + g * 8);
#pragma unroll
    for (int nj = 0; nj < 4; ++nj)
      b[nj] = *(const bf16x8*)(sB + (wc*64 + nj*16 + c16) * 32 + g * 8);
#pragma unroll
    for (int mi = 0; mi < 4; ++mi)
#pragma unroll
      for (int nj = 0; nj < 4; ++nj)
        acc[mi][nj] = __builtin_amdgcn_mfma_f32_16x16x32_bf16(a[mi], b[nj], acc[mi][nj], 0, 0, 0);
    __syncthreads();
  }

#pragma unroll
  for (int mi = 0; mi < 4; ++mi) {
#pragma unroll
    for (int nj = 0; nj < 4; ++nj) {
      int gcol = n0 + wc*64 + nj*16 + c16;
#pragma unroll
      for (int jj = 0; jj < 4; ++jj) {
        int grow = m0 + wr*64 + mi*16 + g*4 + jj;
        float v = acc[mi][nj][jj] * scale;
        size_t oidx;
        if (OUT_MODE == 0) oidx = (size_t)grow * N + gcol;
        else               oidx = ((size_t)(grow >> 11) * 512 + gcol) * 2048 + (grow & 2047);
        if constexpr (sizeof(OutT) == 2) C[oidx] = (OutT)f2bf(v);
        else                             C[oidx] = v;
      }
    }
  }
}

// ---------------- causal GQA flash attention ----------------
// Q: [b][t][h*64+d] bf16 (pre-scaled by 0.125), K: [b][t][kvh*64+d] bf16,
// VT: [b][kvh*64+d][t] bf16, Y: [b][t][h*64+d] bf16.
// Per wave: 32 q-rows, KBLK=64, swapped-operand MFMA (S^T / O^T), no barriers.
__global__ __launch_bounds__(256) void attn_kernel(const ushort* __restrict__ Qb,
                                                   const ushort* __restrict__ Kb,
                                                   const ushort* __restrict__ VTb,
                                                   ushort* __restrict__ Yb) {
  __shared__ ushort sP[4][32 * 64];  // per-wave P buffer, XOR-swizzled
  const int tid = threadIdx.x, w = tid >> 6, l = tid & 63;
  const int g = l >> 4, c16 = l & 15;
  const int W = blockIdx.x * 4 + w;
  const int qt = W & 63, h = (W >> 6) & 31, b = W >> 11;
  const int q0 = qt * 32, kvh = h >> 2;
  const ushort* Qp  = Qb  + ((size_t)(b * TSEQ + q0)) * 2048 + h * 64;
  const ushort* Kp  = Kb  + (size_t)(b * TSEQ) * 512 + kvh * 64;
  const ushort* VTp = VTb + ((size_t)(b * 512 + kvh * 64)) * 2048;
  char* sPw = (char*)&sP[w][0];

  // hoist Q fragments: B-operand of swapped QK^T  (Q[q][d] contiguous in d)
  bf16x8 bq[2][2];
#pragma unroll
  for (int qf = 0; qf < 2; ++qf)
#pragma unroll
    for (int dc = 0; dc < 2; ++dc)
      bq[qf][dc] = *(const bf16x8*)(Qp + (size_t)(qf*16 + c16) * 2048 + dc*32 + g*8);

  float m[2] = {-1e30f, -1e30f}, lsum[2] = {0.f, 0.f};
  f32x4 accO[4][2] = {};
  const int kt_last = (q0 + 31) >> 6;

  for (int kt = 0; kt <= kt_last; ++kt) {
    // ---- S^T = K @ Q^T  (A = K fragment, direct global load, contiguous d)
    f32x4 s[4][2] = {};
#pragma unroll
    for (int dc = 0; dc < 2; ++dc) {
      bf16x8 aK[4];
#pragma unroll
      for (int kf = 0; kf < 4; ++kf)
        aK[kf] = *(const bf16x8*)(Kp + (size_t)(kt*64 + kf*16 + c16) * 512 + dc*32 + g*8);
#pragma unroll
      for (int kf = 0; kf < 4; ++kf)
#pragma unroll
        for (int qf = 0; qf < 2; ++qf)
          s[kf][qf] = __builtin_amdgcn_mfma_f32_16x16x32_bf16(aK[kf], bq[qf][dc], s[kf][qf], 0, 0, 0);
    }
    // ---- causal mask (diagonal tile only)
    if (kt == kt_last) {
#pragma unroll
      for (int kf = 0; kf < 4; ++kf)
#pragma unroll
        for (int qf = 0; qf < 2; ++qf)
#pragma unroll
          for (int j = 0; j < 4; ++j)
            if (kt*64 + kf*16 + g*4 + j > q0 + qf*16 + c16) s[kf][qf][j] = -1e30f;
    }
    // ---- online softmax (per-lane q = qf*16 + c16; cross-group reduce only)
#pragma unroll
    for (int qf = 0; qf < 2; ++qf) {
      float tmax = -1e30f;
#pragma unroll
      for (int kf = 0; kf < 4; ++kf)
#pragma unroll
        for (int j = 0; j < 4; ++j) tmax = fmaxf(tmax, s[kf][qf][j]);
      tmax = fmaxf(tmax, __shfl_xor(tmax, 16));
      tmax = fmaxf(tmax, __shfl_xor(tmax, 32));
      float newm = fmaxf(m[qf], tmax);
      float sc = exp2f((m[qf] - newm) * 1.44269504f);
      m[qf] = newm;
      float tl = 0.f;
#pragma unroll
      for (int kf = 0; kf < 4; ++kf)
#pragma unroll
        for (int j = 0; j < 4; ++j) {
          float p = exp2f((s[kf][qf][j] - newm) * 1.44269504f);
          s[kf][qf][j] = p;
          tl += p;
        }
      tl += __shfl_xor(tl, 16);
      tl += __shfl_xor(tl, 32);
      lsum[qf] = lsum[qf] * sc + tl;
#pragma unroll
      for (int df = 0; df < 4; ++df) accO[df][qf] = accO[df][qf] * sc;
    }
    // ---- P[q][kpos] -> per-wave LDS (bf16, XOR swizzle byte ^= (q&7)<<4)
#pragma unroll
    for (int qf = 0; qf < 2; ++qf) {
      int q = qf*16 + c16;
#pragma unroll
      for (int kf = 0; kf < 4; ++kf)
#pragma unroll
        for (int j = 0; j < 4; j += 2) {
          int kpos = kf*16 + g*4 + j;
          unsigned pk = (unsigned)f2bf(s[kf][qf][j]) | ((unsigned)f2bf(s[kf][qf][j+1]) << 16);
          int byte = (q*128 + kpos*2) ^ ((q & 7) << 4);
          *(unsigned*)(sPw + byte) = pk;
        }
    }
    // ---- O^T += V^T @ P^T  (A = V^T fragment from global, B = P^T from LDS)
#pragma unroll
    for (int cc = 0; cc < 2; ++cc) {
      bf16x8 bp[2];
#pragma unroll
      for (int qf = 0; qf < 2; ++qf) {
        int q = qf*16 + c16;
        int byte = (q*128 + cc*64 + g*16) ^ ((q & 7) << 4);
        bp[qf] = *(const bf16x8*)(sPw + byte);
      }
      bf16x8 aV[4];
#pragma unroll
      for (int df = 0; df < 4; ++df)
        aV[df] = *(const bf16x8*)(VTp + (size_t)(df*16 + c16) * 2048 + kt*64 + cc*32 + g*8);
#pragma unroll
      for (int df = 0; df < 4; ++df)
#pragma unroll
        for (int qf = 0; qf < 2; ++qf)
          accO[df][qf] = __builtin_amdgcn_mfma_f32_16x16x32_bf16(aV[df], bp[qf], accO[df][qf], 0, 0, 0);
    }
  }
  // ---- epilogue: O = O^T / l, write Y[b][t][h*64+d]
#pragma unroll
  for (int qf = 0; qf < 2; ++qf) {
    float inv = 1.f / lsum[qf];
#pragma unroll
    for (int df = 0; df < 4; ++df) {
      ushort4 o;
      o.x = f2bf(accO[df][qf][0] * inv);
      o.y = f2bf(accO[df][qf][1] * inv);
      o.z = f2bf(accO[df][qf][2] * inv);
      o.w = f2bf(accO[df][qf][3] * inv);
      *(ushort4*)(Yb + ((size_t)(b * TSEQ + q0 + qf*16 + c16)) * 2048 + h*64 + df*16 + g*4) = o;
    }
  }
}

extern "C" void kernel_launch(void* const* d_in, const int* in_sizes, int n_in,
                              void* d_out, int out_size, void* d_ws, size_t ws_size,
                              hipStream_t stream) {
  const float* x  = (const float*)d_in[0];
  // d_in[1] = attn_mask: pure causal -1e9 mask, implemented analytically
  const float* Wq = (const float*)d_in[2];
  const float* Wk = (const float*)d_in[3];
  const float* Wv = (const float*)d_in[4];
  const float* Wo = (const float*)d_in[5];
  float* out = (float*)d_out;
  char* ws = (char*)d_ws;
  const size_t MB = 1024 * 1024;
  ushort* xb  = (ushort*)(ws);            // 16 MB  [4096][2048]  (reused as Yb)
  ushort* WqT = (ushort*)(ws + 16*MB);    //  8 MB  [2048][2048]
  ushort* WkT = (ushort*)(ws + 24*MB);    //  2 MB  [512][2048]
  ushort* WvT = (ushort*)(ws + 26*MB);    //  2 MB  [512][2048]
  ushort* WoT = (ushort*)(ws + 28*MB);    //  8 MB  [2048][2048]
  ushort* Qb  = (ushort*)(ws + 36*MB);    // 16 MB  [4096][2048]
  ushort* Kb  = (ushort*)(ws + 52*MB);    //  4 MB  [4096][512]
  ushort* VTb = (ushort*)(ws + 56*MB);    //  4 MB  [2][512][2048]
  ushort* Yb  = xb;                       // aliases xb (x dead after projections)

  cvt_kernel<<<8192, 256, 0, stream>>>(x, xb, 2097152);
  tcvt_kernel<<<dim3(2048/32, 2048/32), 256, 0, stream>>>(Wq, WqT, 2048, 2048);
  tcvt_kernel<<<dim3(512/32,  2048/32), 256, 0, stream>>>(Wk, WkT, 2048, 512);
  tcvt_kernel<<<dim3(512/32,  2048/32), 256, 0, stream>>>(Wv, WvT, 2048, 512);
  tcvt_kernel<<<dim3(2048/32, 2048/32), 256, 0, stream>>>(Wo, WoT, 2048, 2048);

  // Q = (x @ Wq) * 0.125  (attention scale folded in)
  gemm_bt<ushort, 0><<<dim3(2048/128, 4096/128), 256, 0, stream>>>(xb, WqT, Qb, MROWS, 2048, 2048, 0.125f);
  gemm_bt<ushort, 0><<<dim3(512/128,  4096/128), 256, 0, stream>>>(xb, WkT, Kb, MROWS, 512, 2048, 1.0f);
  gemm_bt<ushort, 1><<<dim3(512/128,  4096/128), 256, 0, stream>>>(xb, WvT, VTb, MROWS, 512, 2048, 1.0f);

  attn_kernel<<<1024, 256, 0, stream>>>(Qb, Kb, VTb, Yb);

  gemm_bt<float, 0><<<dim3(2048/128, 4096/128), 256, 0, stream>>>(Yb, WoT, out, MROWS, 2048, 2048, 1.0f);
}

// Round 3
// 423.019 us; speedup vs baseline: 1.3398x; 1.3398x over previous
//
#include <hip/hip_runtime.h>
#include <hip/hip_bf16.h>
#include <cmath>

#define HIDDEN 2048
#define NHEADS 32
#define NKVH   8
#define HD     64
#define BB     2
#define TSEQ   2048
#define MROWS  (BB*TSEQ)   // 4096

typedef __attribute__((ext_vector_type(8))) short bf16x8;
typedef __attribute__((ext_vector_type(4))) float f32x4;

__device__ __forceinline__ ushort f2bf(float f) {
  union { float f; unsigned u; } x; x.f = f;
  unsigned r = x.u + 0x7fffu + ((x.u >> 16) & 1u);
  return (ushort)(r >> 16);
}

__device__ __forceinline__ void async16(ushort* lds, const ushort* g) {
  __builtin_amdgcn_global_load_lds(
      (const __attribute__((address_space(1))) unsigned int*)g,
      (__attribute__((address_space(3))) unsigned int*)lds, 16, 0, 0);
}

// ---------------- fp32 -> bf16 elementwise ----------------
__global__ void cvt_kernel(const float* __restrict__ in, ushort* __restrict__ out, int n4) {
  int i = blockIdx.x * blockDim.x + threadIdx.x;
  if (i < n4) {
    float4 v = ((const float4*)in)[i];
    ushort4 o;
    o.x = f2bf(v.x); o.y = f2bf(v.y); o.z = f2bf(v.z); o.w = f2bf(v.w);
    ((ushort4*)out)[i] = o;
  }
}

// ---------------- fp32 [R][C] -> bf16 [C][R] transpose-convert ----------------
__global__ void tcvt_kernel(const float* __restrict__ in, ushort* __restrict__ out, int R, int C) {
  __shared__ float tile[32][33];
  int tx = threadIdx.x & 31, ty = threadIdx.x >> 5;   // ty 0..7
  int c0 = blockIdx.x * 32, r0 = blockIdx.y * 32;
#pragma unroll
  for (int i = 0; i < 4; ++i)
    tile[ty*4 + i][tx] = in[(size_t)(r0 + ty*4 + i) * C + c0 + tx];
  __syncthreads();
#pragma unroll
  for (int i = 0; i < 4; ++i)
    out[(size_t)(c0 + ty*4 + i) * R + r0 + tx] = f2bf(tile[tx][ty*4 + i]);
}

// ---------------- bf16 GEMM: C[M][N] = A[M][K] @ BT[N][K]^T ----------------
// OUT_MODE 0: C[m*N+n]
// OUT_MODE 1 (V^T): C[((m>>11)*512 + n)*2048 + (m&2047)]
// OUT_MODE 2 (fused K|V, N=1024): n<512 -> K[m*512+n];
//            n>=512 -> (2^21 elems in) + ((m>>11)*512 + n-512)*2048 + (m&2047)
template<typename OutT, int OUT_MODE>
__global__ __launch_bounds__(256) void gemm_bt(const ushort* __restrict__ A,
                                               const ushort* __restrict__ BT,
                                               OutT* __restrict__ C,
                                               int M, int N, int K, float scale) {
  __shared__ ushort sA[128 * 32];
  __shared__ ushort sB[128 * 32];
  const int tid = threadIdx.x;
  const int w = tid >> 6, l = tid & 63;
  const int wr = w >> 1, wc = w & 1;
  const int g = l >> 4, c16 = l & 15;
  const int m0 = blockIdx.y * 128, n0 = blockIdx.x * 128;

  const int sr = l >> 2;          // staging row within 16-row stripe
  const int sc = (l & 3) * 8;     // staging col (elems)
  const ushort* gA[2]; const ushort* gB[2];
  ushort* lA[2]; ushort* lB[2];
#pragma unroll
  for (int ii = 0; ii < 2; ++ii) {
    int inst = w * 2 + ii;
    gA[ii] = A  + (size_t)(m0 + inst*16 + sr) * K + sc;
    gB[ii] = BT + (size_t)(n0 + inst*16 + sr) * K + sc;
    lA[ii] = sA + inst * 512 + l * 8;
    lB[ii] = sB + inst * 512 + l * 8;
  }

  f32x4 acc[4][4] = {};

  for (int k0 = 0; k0 < K; k0 += 32) {
    async16(lA[0], gA[0] + k0);
    async16(lA[1], gA[1] + k0);
    async16(lB[0], gB[0] + k0);
    async16(lB[1], gB[1] + k0);
    __syncthreads();
    bf16x8 a[4], b[4];
#pragma unroll
    for (int mi = 0; mi < 4; ++mi)
      a[mi] = *(const bf16x8*)(sA + (wr*64 + mi*16 + c16) * 32 + g * 8);
#pragma unroll
    for (int nj = 0; nj < 4; ++nj)
      b[nj] = *(const bf16x8*)(sB + (wc*64 + nj*16 + c16) * 32 + g * 8);
#pragma unroll
    for (int mi = 0; mi < 4; ++mi)
#pragma unroll
      for (int nj = 0; nj < 4; ++nj)
        acc[mi][nj] = __builtin_amdgcn_mfma_f32_16x16x32_bf16(a[mi], b[nj], acc[mi][nj], 0, 0, 0);
    __syncthreads();
  }

#pragma unroll
  for (int mi = 0; mi < 4; ++mi) {
#pragma unroll
    for (int nj = 0; nj < 4; ++nj) {
      int gcol = n0 + wc*64 + nj*16 + c16;
#pragma unroll
      for (int jj = 0; jj < 4; ++jj) {
        int grow = m0 + wr*64 + mi*16 + g*4 + jj;
        float v = acc[mi][nj][jj] * scale;
        size_t oidx;
        if (OUT_MODE == 0) oidx = (size_t)grow * N + gcol;
        else if (OUT_MODE == 1) oidx = ((size_t)(grow >> 11) * 512 + gcol) * 2048 + (grow & 2047);
        else {
          if (gcol < 512) oidx = (size_t)grow * 512 + gcol;
          else oidx = ((size_t)1 << 21) + ((size_t)(grow >> 11) * 512 + (gcol - 512)) * 2048 + (grow & 2047);
        }
        if constexpr (sizeof(OutT) == 2) C[oidx] = (OutT)f2bf(v);
        else                             C[oidx] = v;
      }
    }
  }
}

// ---------------- causal GQA flash attention ----------------
// Q: [b][t][h*64+d] bf16 (pre-scaled by 0.125), K: [b][t][kvh*64+d] bf16,
// VT: [b][kvh*64+d][t] bf16, Y: [b][t][h*64+d] bf16.
// One wave per block, 32 q-rows/wave, KBLK=64, swapped-operand MFMA.
// K prefetched one tile ahead (ping-pong regs, dual-body loop = static idx);
// V issued at body top so its latency hides under QK+softmax.
// Dispatch order: descending qt (heavy blocks first) for tail packing.
__global__ __launch_bounds__(64, 2) void attn_kernel(const ushort* __restrict__ Qb,
                                                     const ushort* __restrict__ Kb,
                                                     const ushort* __restrict__ VTb,
                                                     ushort* __restrict__ Yb) {
  __shared__ ushort sP[32 * 64];  // per-block (1-wave) P buffer, XOR-swizzled
  const int l = threadIdx.x;
  const int g = l >> 4, c16 = l & 15;
  const int bid = blockIdx.x;
  const int qt = 63 - (bid >> 6);          // heavy q-tiles dispatched first
  const int h = bid & 31, b = (bid >> 5) & 1;
  const int q0 = qt * 32, kvh = h >> 2;
  const ushort* Qp  = Qb  + ((size_t)(b * TSEQ + q0)) * 2048 + h * 64;
  const ushort* Kp  = Kb  + (size_t)(b * TSEQ) * 512 + kvh * 64;
  const ushort* VTp = VTb + ((size_t)(b * 512 + kvh * 64)) * 2048;
  char* sPw = (char*)sP;

  // hoist Q fragments (B-operand of swapped QK^T)
  bf16x8 bq[2][2];
#pragma unroll
  for (int qf = 0; qf < 2; ++qf)
#pragma unroll
    for (int dc = 0; dc < 2; ++dc)
      bq[qf][dc] = *(const bf16x8*)(Qp + (size_t)(qf*16 + c16) * 2048 + dc*32 + g*8);

  float m[2] = {-1e30f, -1e30f}, lsum[2] = {0.f, 0.f};
  f32x4 accO[4][2] = {};
  const int kt_last = (q0 + 31) >> 6;

  bf16x8 aKa[8], aKb[8], aV[8];

  auto loadK = [&](int kt, bf16x8* a) {
#pragma unroll
    for (int dc = 0; dc < 2; ++dc)
#pragma unroll
      for (int kf = 0; kf < 4; ++kf)
        a[dc*4 + kf] = *(const bf16x8*)(Kp + (size_t)(kt*64 + kf*16 + c16) * 512 + dc*32 + g*8);
  };

  auto body = [&](const bf16x8* aK, int kt) {
    // V loads issued first: latency hides under QK^T + softmax
#pragma unroll
    for (int cc = 0; cc < 2; ++cc)
#pragma unroll
      for (int df = 0; df < 4; ++df)
        aV[cc*4 + df] = *(const bf16x8*)(VTp + (size_t)(df*16 + c16) * 2048 + kt*64 + cc*32 + g*8);

    // ---- S^T = K @ Q^T
    f32x4 s[4][2] = {};
#pragma unroll
    for (int dc = 0; dc < 2; ++dc)
#pragma unroll
      for (int kf = 0; kf < 4; ++kf)
#pragma unroll
        for (int qf = 0; qf < 2; ++qf)
          s[kf][qf] = __builtin_amdgcn_mfma_f32_16x16x32_bf16(aK[dc*4 + kf], bq[qf][dc], s[kf][qf], 0, 0, 0);

    // ---- causal mask (diagonal tile only)
    if (kt == kt_last) {
#pragma unroll
      for (int kf = 0; kf < 4; ++kf)
#pragma unroll
        for (int qf = 0; qf < 2; ++qf)
#pragma unroll
          for (int j = 0; j < 4; ++j)
            if (kt*64 + kf*16 + g*4 + j > q0 + qf*16 + c16) s[kf][qf][j] = -1e30f;
    }

    // ---- online softmax (per-lane q = qf*16+c16; reduce across 4 lane-groups)
#pragma unroll
    for (int qf = 0; qf < 2; ++qf) {
      float tmax = -1e30f;
#pragma unroll
      for (int kf = 0; kf < 4; ++kf)
#pragma unroll
        for (int j = 0; j < 4; ++j) tmax = fmaxf(tmax, s[kf][qf][j]);
      tmax = fmaxf(tmax, __shfl_xor(tmax, 16));
      tmax = fmaxf(tmax, __shfl_xor(tmax, 32));
      float newm = fmaxf(m[qf], tmax);
      float sc = exp2f((m[qf] - newm) * 1.44269504f);
      m[qf] = newm;
      float tl = 0.f;
#pragma unroll
      for (int kf = 0; kf < 4; ++kf)
#pragma unroll
        for (int j = 0; j < 4; ++j) {
          float p = exp2f((s[kf][qf][j] - newm) * 1.44269504f);
          s[kf][qf][j] = p;
          tl += p;
        }
      tl += __shfl_xor(tl, 16);
      tl += __shfl_xor(tl, 32);
      lsum[qf] = lsum[qf] * sc + tl;
#pragma unroll
      for (int df = 0; df < 4; ++df) accO[df][qf] = accO[df][qf] * sc;
    }

    // ---- P -> LDS (bf16, XOR swizzle byte ^= (q&7)<<4), 8B writes
#pragma unroll
    for (int qf = 0; qf < 2; ++qf) {
      int q = qf*16 + c16;
#pragma unroll
      for (int kf = 0; kf < 4; ++kf) {
        uint2 pk;
        pk.x = (unsigned)f2bf(s[kf][qf][0]) | ((unsigned)f2bf(s[kf][qf][1]) << 16);
        pk.y = (unsigned)f2bf(s[kf][qf][2]) | ((unsigned)f2bf(s[kf][qf][3]) << 16);
        int byte = (q*128 + (kf*16 + g*4)*2) ^ ((q & 7) << 4);
        *(uint2*)(sPw + byte) = pk;
      }
    }

    // ---- O^T += V^T @ P^T
#pragma unroll
    for (int cc = 0; cc < 2; ++cc) {
      bf16x8 bp[2];
#pragma unroll
      for (int qf = 0; qf < 2; ++qf) {
        int q = qf*16 + c16;
        int byte = (q*128 + cc*64 + g*16) ^ ((q & 7) << 4);
        bp[qf] = *(const bf16x8*)(sPw + byte);
      }
#pragma unroll
      for (int df = 0; df < 4; ++df)
#pragma unroll
        for (int qf = 0; qf < 2; ++qf)
          accO[df][qf] = __builtin_amdgcn_mfma_f32_16x16x32_bf16(aV[cc*4 + df], bp[qf], accO[df][qf], 0, 0, 0);
    }
  };

  loadK(0, aKa);
  int kt = 0;
  for (;;) {
    if (kt < kt_last) loadK(kt + 1, aKb);
    body(aKa, kt);
    if (kt++ == kt_last) break;
    if (kt < kt_last) loadK(kt + 1, aKa);
    body(aKb, kt);
    if (kt++ == kt_last) break;
  }

  // ---- epilogue: O = O^T / l, write Y[b][t][h*64+d]
#pragma unroll
  for (int qf = 0; qf < 2; ++qf) {
    float inv = 1.f / lsum[qf];
#pragma unroll
    for (int df = 0; df < 4; ++df) {
      ushort4 o;
      o.x = f2bf(accO[df][qf][0] * inv);
      o.y = f2bf(accO[df][qf][1] * inv);
      o.z = f2bf(accO[df][qf][2] * inv);
      o.w = f2bf(accO[df][qf][3] * inv);
      *(ushort4*)(Yb + ((size_t)(b * TSEQ + q0 + qf*16 + c16)) * 2048 + h*64 + df*16 + g*4) = o;
    }
  }
}

extern "C" void kernel_launch(void* const* d_in, const int* in_sizes, int n_in,
                              void* d_out, int out_size, void* d_ws, size_t ws_size,
                              hipStream_t stream) {
  const float* x  = (const float*)d_in[0];
  // d_in[1] = attn_mask: pure causal -1e9 mask, implemented analytically
  const float* Wq = (const float*)d_in[2];
  const float* Wk = (const float*)d_in[3];
  const float* Wv = (const float*)d_in[4];
  const float* Wo = (const float*)d_in[5];
  float* out = (float*)d_out;
  char* ws = (char*)d_ws;
  const size_t MB = 1024 * 1024;
  ushort* xb  = (ushort*)(ws);            // 16 MB  [4096][2048]  (reused as Yb)
  ushort* WqT = (ushort*)(ws + 16*MB);    //  8 MB  [2048][2048]
  ushort* WkT = (ushort*)(ws + 24*MB);    //  2 MB  [512][2048]   (contiguous with WvT)
  ushort* WvT = (ushort*)(ws + 26*MB);    //  2 MB  [512][2048]
  ushort* WoT = (ushort*)(ws + 28*MB);    //  8 MB  [2048][2048]
  ushort* Qb  = (ushort*)(ws + 36*MB);    // 16 MB  [4096][2048]
  ushort* Kb  = (ushort*)(ws + 52*MB);    //  4 MB  [4096][512]   (contiguous with VTb)
  ushort* VTb = (ushort*)(ws + 56*MB);    //  4 MB  [2][512][2048]
  ushort* Yb  = xb;                       // aliases xb (x dead after projections)

  cvt_kernel<<<8192, 256, 0, stream>>>(x, xb, 2097152);
  tcvt_kernel<<<dim3(2048/32, 2048/32), 256, 0, stream>>>(Wq, WqT, 2048, 2048);
  tcvt_kernel<<<dim3(512/32,  2048/32), 256, 0, stream>>>(Wk, WkT, 2048, 512);
  tcvt_kernel<<<dim3(512/32,  2048/32), 256, 0, stream>>>(Wv, WvT, 2048, 512);
  tcvt_kernel<<<dim3(2048/32, 2048/32), 256, 0, stream>>>(Wo, WoT, 2048, 2048);

  // Q = (x @ Wq) * 0.125  (attention scale folded in)
  gemm_bt<ushort, 0><<<dim3(2048/128, 4096/128), 256, 0, stream>>>(xb, WqT, Qb, MROWS, 2048, 2048, 0.125f);
  // fused K|V projection: BT = [WkT; WvT] (contiguous), split-destination epilogue
  gemm_bt<ushort, 2><<<dim3(1024/128, 4096/128), 256, 0, stream>>>(xb, WkT, Kb, MROWS, 1024, 2048, 1.0f);

  attn_kernel<<<4096, 64, 0, stream>>>(Qb, Kb, VTb, Yb);

  gemm_bt<float, 0><<<dim3(2048/128, 4096/128), 256, 0, stream>>>(Yb, WoT, out, MROWS, 2048, 2048, 1.0f);
}